// Round 9
// baseline (162.672 us; speedup 1.0000x reference)
//
#include <hip/hip_runtime.h>

// SimpleRNN: B=8192, T=1024, H=8.
// v4: TWO batches per quad, stage-major interleaved instruction stream.
// Theory: 1 wave/SIMD + in-order issue => every dep-use stall (~3.5cy) is exposed;
// adjacent-independent ops (batch a / batch b alternating) fill the stalls.
// Math per batch identical to v2: weights pre-scaled by 2/ln2, tanh = fma(-2, rcp(exp2(u)+1), 1).

#define T_LEN 1024
#define DPP_XOR1 0xB1  // quad_perm(1,0,3,2)
#define DPP_XOR2 0x4E  // quad_perm(2,3,0,1)
#define DPP_XOR3 0x1B  // quad_perm(3,2,1,0)
#define TWO_OVER_LN2 2.8853900817779268f

template <int CTRL>
__device__ __forceinline__ float fdpp(float v) {
    int i = __builtin_bit_cast(int, v);
    int r = __builtin_amdgcn_mov_dpp(i, CTRL, 0xF, 0xF, true);
    return __builtin_bit_cast(float, r);
}

__device__ __forceinline__ float fast_sigmoid(float z) {
    float e = __builtin_amdgcn_exp2f(z * -1.4426950408889634f);
    return __builtin_amdgcn_rcpf(1.0f + e);
}

struct Wq { float wA[4], wB[4], wC[4], wD[4]; };

// Two-batch interleaved step. All inputs pre-scaled by 2/ln2.
__device__ __forceinline__ void step2(float xa, float xb,
                                      float& h0a, float& h1a, float& h0b, float& h1b,
                                      const Wq& w, float wih0, float wih1,
                                      float bias0, float bias1) {
    // input projection (off-chain)
    float pa0 = __builtin_fmaf(xa, wih0, bias0);
    float pb0 = __builtin_fmaf(xb, wih0, bias0);
    float pa1 = __builtin_fmaf(xa, wih1, bias1);
    float pb1 = __builtin_fmaf(xb, wih1, bias1);

    // all cross-lane reads hoisted; h0*,h1* were written ~30 instrs ago (no DPP hazard)
    float a1 = fdpp<DPP_XOR1>(h0a), b1 = fdpp<DPP_XOR1>(h0b);
    float c1 = fdpp<DPP_XOR1>(h1a), d1 = fdpp<DPP_XOR1>(h1b);
    float a2 = fdpp<DPP_XOR2>(h0a), b2 = fdpp<DPP_XOR2>(h0b);
    float c2 = fdpp<DPP_XOR2>(h1a), d2 = fdpp<DPP_XOR2>(h1b);
    float a3 = fdpp<DPP_XOR3>(h0a), b3 = fdpp<DPP_XOR3>(h0b);
    float c3 = fdpp<DPP_XOR3>(h1a), d3 = fdpp<DPP_XOR3>(h1b);

    // 8 independent accumulation chains (2 batches x {u0,v0,u1,v1}), interleaved
    float ua0 = __builtin_fmaf(h0a, w.wA[0], pa0);
    float ub0 = __builtin_fmaf(h0b, w.wA[0], pb0);
    float va0 = h1a * w.wB[0];
    float vb0 = h1b * w.wB[0];
    float ua1 = __builtin_fmaf(h0a, w.wC[0], pa1);
    float ub1 = __builtin_fmaf(h0b, w.wC[0], pb1);
    float va1 = h1a * w.wD[0];
    float vb1 = h1b * w.wD[0];

    ua0 = __builtin_fmaf(a1, w.wA[1], ua0);  ub0 = __builtin_fmaf(b1, w.wA[1], ub0);
    va0 = __builtin_fmaf(c1, w.wB[1], va0);  vb0 = __builtin_fmaf(d1, w.wB[1], vb0);
    ua1 = __builtin_fmaf(a1, w.wC[1], ua1);  ub1 = __builtin_fmaf(b1, w.wC[1], ub1);
    va1 = __builtin_fmaf(c1, w.wD[1], va1);  vb1 = __builtin_fmaf(d1, w.wD[1], vb1);

    ua0 = __builtin_fmaf(a2, w.wA[2], ua0);  ub0 = __builtin_fmaf(b2, w.wA[2], ub0);
    va0 = __builtin_fmaf(c2, w.wB[2], va0);  vb0 = __builtin_fmaf(d2, w.wB[2], vb0);
    ua1 = __builtin_fmaf(a2, w.wC[2], ua1);  ub1 = __builtin_fmaf(b2, w.wC[2], ub1);
    va1 = __builtin_fmaf(c2, w.wD[2], va1);  vb1 = __builtin_fmaf(d2, w.wD[2], vb1);

    ua0 = __builtin_fmaf(a3, w.wA[3], ua0);  ub0 = __builtin_fmaf(b3, w.wA[3], ub0);
    va0 = __builtin_fmaf(c3, w.wB[3], va0);  vb0 = __builtin_fmaf(d3, w.wB[3], vb0);
    ua1 = __builtin_fmaf(a3, w.wC[3], ua1);  ub1 = __builtin_fmaf(b3, w.wC[3], ub1);
    va1 = __builtin_fmaf(c3, w.wD[3], va1);  vb1 = __builtin_fmaf(d3, w.wD[3], vb1);

    float za0 = ua0 + va0, zb0 = ub0 + vb0;
    float za1 = ua1 + va1, zb1 = ub1 + vb1;

    // 4 interleaved tanh tails
    float ea0 = __builtin_amdgcn_exp2f(za0);
    float eb0 = __builtin_amdgcn_exp2f(zb0);
    float ea1 = __builtin_amdgcn_exp2f(za1);
    float eb1 = __builtin_amdgcn_exp2f(zb1);
    float ra0 = __builtin_amdgcn_rcpf(ea0 + 1.0f);
    float rb0 = __builtin_amdgcn_rcpf(eb0 + 1.0f);
    float ra1 = __builtin_amdgcn_rcpf(ea1 + 1.0f);
    float rb1 = __builtin_amdgcn_rcpf(eb1 + 1.0f);
    h0a = __builtin_fmaf(-2.0f, ra0, 1.0f);
    h0b = __builtin_fmaf(-2.0f, rb0, 1.0f);
    h1a = __builtin_fmaf(-2.0f, ra1, 1.0f);
    h1b = __builtin_fmaf(-2.0f, rb1, 1.0f);
}

__global__ __launch_bounds__(64, 1) void rnn_quad2_kernel(
    const float* __restrict__ x, const float* __restrict__ W_ih,
    const float* __restrict__ W_hh, const float* __restrict__ b_ih,
    const float* __restrict__ b_hh, const float* __restrict__ W_fc,
    const float* __restrict__ b_fc, float* __restrict__ out, int B)
{
    const int tid = blockIdx.x * 64 + threadIdx.x;
    const int p = tid & 3;
    const int q = tid >> 2;          // quad id; serves batches 2q, 2q+1
    const int ba = 2 * q;
    const int bb = ba + 1;
    if (bb >= B) return;

    Wq w;
#pragma unroll
    for (int r = 0; r < 4; ++r) {
        const int k = p ^ r;
        w.wA[r] = W_hh[p * 8 + k]           * TWO_OVER_LN2;
        w.wB[r] = W_hh[p * 8 + k + 4]       * TWO_OVER_LN2;
        w.wC[r] = W_hh[(p + 4) * 8 + k]     * TWO_OVER_LN2;
        w.wD[r] = W_hh[(p + 4) * 8 + k + 4] * TWO_OVER_LN2;
    }
    const float wih0  = W_ih[p]     * TWO_OVER_LN2;
    const float wih1  = W_ih[p + 4] * TWO_OVER_LN2;
    const float bias0 = (b_ih[p] + b_hh[p])         * TWO_OVER_LN2;
    const float bias1 = (b_ih[p + 4] + b_hh[p + 4]) * TWO_OVER_LN2;
    const float wfc0 = W_fc[p], wfc1 = W_fc[p + 4];
    const float bfc = b_fc[0];

    const float* xA = x + (size_t)ba * T_LEN;
    const float* xB = x + (size_t)bb * T_LEN;
    float h0a = 0.0f, h1a = 0.0f, h0b = 0.0f, h1b = 0.0f;

    float4 cA0 = *(const float4*)(xA + 0), cA1 = *(const float4*)(xA + 4);
    float4 cB0 = *(const float4*)(xB + 0), cB1 = *(const float4*)(xB + 4);
    float4 nA0 = *(const float4*)(xA + 8), nA1 = *(const float4*)(xA + 12);
    float4 nB0 = *(const float4*)(xB + 8), nB1 = *(const float4*)(xB + 12);

#pragma unroll 1
    for (int t0 = 0; t0 < T_LEN; t0 += 8) {
        float4 pA0, pA1, pB0, pB1;
        const bool more = (t0 + 16) < T_LEN;
        if (more) {
            pA0 = *(const float4*)(xA + t0 + 16);
            pA1 = *(const float4*)(xA + t0 + 20);
            pB0 = *(const float4*)(xB + t0 + 16);
            pB1 = *(const float4*)(xB + t0 + 20);
        }
        step2(cA0.x, cB0.x, h0a, h1a, h0b, h1b, w, wih0, wih1, bias0, bias1);
        step2(cA0.y, cB0.y, h0a, h1a, h0b, h1b, w, wih0, wih1, bias0, bias1);
        step2(cA0.z, cB0.z, h0a, h1a, h0b, h1b, w, wih0, wih1, bias0, bias1);
        step2(cA0.w, cB0.w, h0a, h1a, h0b, h1b, w, wih0, wih1, bias0, bias1);
        step2(cA1.x, cB1.x, h0a, h1a, h0b, h1b, w, wih0, wih1, bias0, bias1);
        step2(cA1.y, cB1.y, h0a, h1a, h0b, h1b, w, wih0, wih1, bias0, bias1);
        step2(cA1.z, cB1.z, h0a, h1a, h0b, h1b, w, wih0, wih1, bias0, bias1);
        step2(cA1.w, cB1.w, h0a, h1a, h0b, h1b, w, wih0, wih1, bias0, bias1);
        cA0 = nA0; cA1 = nA1; cB0 = nB0; cB1 = nB1;
        if (more) { nA0 = pA0; nA1 = pA1; nB0 = pB0; nB1 = pB1; }
    }

    // FC + sigmoid per batch; quad butterfly reduce
    float sa = __builtin_fmaf(h0a, wfc0, h1a * wfc1);
    float sb = __builtin_fmaf(h0b, wfc0, h1b * wfc1);
    sa += fdpp<DPP_XOR1>(sa);
    sb += fdpp<DPP_XOR1>(sb);
    sa += fdpp<DPP_XOR2>(sa);
    sb += fdpp<DPP_XOR2>(sb);
    if (p == 0) {
        out[ba] = fast_sigmoid(sa + bfc);
        out[bb] = fast_sigmoid(sb + bfc);
    }
}

extern "C" void kernel_launch(void* const* d_in, const int* in_sizes, int n_in,
                              void* d_out, int out_size, void* d_ws, size_t ws_size,
                              hipStream_t stream) {
    const float* x    = (const float*)d_in[0];
    const float* W_ih = (const float*)d_in[1];
    const float* W_hh = (const float*)d_in[2];
    const float* b_ih = (const float*)d_in[3];
    const float* b_hh = (const float*)d_in[4];
    const float* W_fc = (const float*)d_in[5];
    const float* b_fc = (const float*)d_in[6];
    float* out = (float*)d_out;

    const int B = in_sizes[0] / T_LEN;            // 8192
    const int threads = (B / 2) * 4;              // one quad per 2 batches
    const int grid = (threads + 63) / 64;         // 256 blocks of 64
    rnn_quad2_kernel<<<grid, 64, 0, stream>>>(x, W_ih, W_hh, b_ih, b_hh, W_fc, b_fc, out, B);
}

// Round 11
// 56.570 us; speedup vs baseline: 2.8756x; 2.8756x over previous
//
#include <hip/hip_runtime.h>

// SimpleRNN: B=8192, T=1024, H=8.
// v5: 8 lanes per batch (lane j owns state r[j]); 1024 waves = 1/SIMD chip-wide.
// Model (r9): per-wave issue cadence ~6 cyc/instr regardless of ILP -> minimize instrs/step.
// State substitution: r = rcp(2^(K z)+1), h = 1-2r; fold -2K into W_hh, rowsum into bias
// => step = 1 preFMA + 7 DPP + 8 FMA + exp2 + add + rcp  (~19 ops vs v2's ~34).
// Shuffles all DPP-speed: xor1/2/3 quad_perm; xor7 row_half_mirror(0x141); xor4/5/6 = qp(mirror).

#define T_LEN 1024
#define DPP_XOR1 0xB1   // quad_perm(1,0,3,2)
#define DPP_XOR2 0x4E   // quad_perm(2,3,0,1)
#define DPP_XOR3 0x1B   // quad_perm(3,2,1,0)
#define DPP_XOR7 0x141  // row_half_mirror: j <-> 7-j within 8-lane group
#define K_2LN2 2.8853900817779268f

template <int CTRL>
__device__ __forceinline__ float fdpp(float v) {
    int i = __builtin_bit_cast(int, v);
    int r = __builtin_amdgcn_mov_dpp(i, CTRL, 0xF, 0xF, true);
    return __builtin_bit_cast(float, r);
}

__device__ __forceinline__ float fast_sigmoid(float z) {
    float e = __builtin_amdgcn_exp2f(z * -1.4426950408889634f);
    return __builtin_amdgcn_rcpf(1.0f + e);
}

// One RNN step on state r (all 8 lanes of the group participate).
// u = pre + sum_m wq[m]*r[j^m];  r' = rcp(2^u + 1)
__device__ __forceinline__ void step(float pre, float& r, const float* wq) {
    float m1 = fdpp<DPP_XOR1>(r);
    float m2 = fdpp<DPP_XOR2>(r);
    float m3 = fdpp<DPP_XOR3>(r);
    float m7 = fdpp<DPP_XOR7>(r);
    float m4 = fdpp<DPP_XOR3>(m7);   // j^7^3 = j^4
    float m5 = fdpp<DPP_XOR2>(m7);   // j^5
    float m6 = fdpp<DPP_XOR1>(m7);   // j^6
    float u = __builtin_fmaf(r,  wq[0], pre);
    u = __builtin_fmaf(m1, wq[1], u);
    u = __builtin_fmaf(m2, wq[2], u);
    u = __builtin_fmaf(m3, wq[3], u);
    u = __builtin_fmaf(m4, wq[4], u);
    u = __builtin_fmaf(m5, wq[5], u);
    u = __builtin_fmaf(m6, wq[6], u);
    u = __builtin_fmaf(m7, wq[7], u);
    float e = __builtin_amdgcn_exp2f(u);
    r = __builtin_amdgcn_rcpf(e + 1.0f);
}

__global__ __launch_bounds__(256) void rnn_oct_kernel(
    const float* __restrict__ x, const float* __restrict__ W_ih,
    const float* __restrict__ W_hh, const float* __restrict__ b_ih,
    const float* __restrict__ b_hh, const float* __restrict__ W_fc,
    const float* __restrict__ b_fc, float* __restrict__ out, int B)
{
    const int tid = blockIdx.x * 256 + threadIdx.x;
    const int j = tid & 7;        // owns state element j
    const int b = tid >> 3;       // batch index
    if (b >= B) return;

    // weights: wq[m] = -2K * W_hh[j][j^m];  rowsum folds into bias
    float wq[8];
    float rowsum = 0.0f;
#pragma unroll
    for (int m = 0; m < 8; ++m) {
        float wv = W_hh[j * 8 + (j ^ m)];
        wq[m] = -2.0f * K_2LN2 * wv;
        rowsum += wv;
    }
    const float biasp = K_2LN2 * (b_ih[j] + b_hh[j] + rowsum);
    const float wihp  = K_2LN2 * W_ih[j];

    const float wfc = W_fc[j];
    float sw = wfc;                       // group-sum of W_fc via DPP butterfly
    sw += fdpp<DPP_XOR1>(sw);
    sw += fdpp<DPP_XOR2>(sw);
    sw += fdpp<DPP_XOR7>(sw);
    const float cfc  = b_fc[0] + sw;      // bfc + sum_j wfc[j]
    const float wfc2 = -2.0f * wfc;

    const float* xb = x + (size_t)b * T_LEN;
    float r = 0.5f;                       // h=0 -> r=0.5

    // 8-step chunks; all 8 group-lanes load the same 32B (HW broadcast); prefetch 1 chunk ahead
    float4 cur0 = *(const float4*)(xb + 0);
    float4 cur1 = *(const float4*)(xb + 4);

#pragma unroll 1
    for (int t0 = 0; t0 < T_LEN; t0 += 8) {
        float4 nxt0, nxt1;
        const bool more = (t0 + 8) < T_LEN;
        if (more) {
            nxt0 = *(const float4*)(xb + t0 + 8);
            nxt1 = *(const float4*)(xb + t0 + 12);
        }
        // input projection hoisted off the chain
        float pre[8];
        pre[0] = __builtin_fmaf(cur0.x, wihp, biasp);
        pre[1] = __builtin_fmaf(cur0.y, wihp, biasp);
        pre[2] = __builtin_fmaf(cur0.z, wihp, biasp);
        pre[3] = __builtin_fmaf(cur0.w, wihp, biasp);
        pre[4] = __builtin_fmaf(cur1.x, wihp, biasp);
        pre[5] = __builtin_fmaf(cur1.y, wihp, biasp);
        pre[6] = __builtin_fmaf(cur1.z, wihp, biasp);
        pre[7] = __builtin_fmaf(cur1.w, wihp, biasp);

#pragma unroll
        for (int i = 0; i < 8; ++i)
            step(pre[i], r, wq);

        if (more) { cur0 = nxt0; cur1 = nxt1; }
    }

    // out[b] = sigmoid(cfc + sum_j wfc2[j]*r[j]); 8-lane DPP butterfly
    float sv = r * wfc2;
    sv += fdpp<DPP_XOR1>(sv);
    sv += fdpp<DPP_XOR2>(sv);
    sv += fdpp<DPP_XOR7>(sv);
    if (j == 0) out[b] = fast_sigmoid(sv + cfc);
}

extern "C" void kernel_launch(void* const* d_in, const int* in_sizes, int n_in,
                              void* d_out, int out_size, void* d_ws, size_t ws_size,
                              hipStream_t stream) {
    const float* x    = (const float*)d_in[0];
    const float* W_ih = (const float*)d_in[1];
    const float* W_hh = (const float*)d_in[2];
    const float* b_ih = (const float*)d_in[3];
    const float* b_hh = (const float*)d_in[4];
    const float* W_fc = (const float*)d_in[5];
    const float* b_fc = (const float*)d_in[6];
    float* out = (float*)d_out;

    const int B = in_sizes[0] / T_LEN;     // 8192
    const int threads = B * 8;             // 8 lanes per batch -> 65536 threads
    const int grid = threads / 256;        // 256 blocks of 256 (4 waves, 1 per SIMD)
    rnn_oct_kernel<<<grid, 256, 0, stream>>>(x, W_ih, W_hh, b_ih, b_hh, W_fc, b_fc, out, B);
}

// Round 14
// 47.520 us; speedup vs baseline: 3.4232x; 1.1904x over previous
//
#include <hip/hip_runtime.h>

// SimpleRNN: B=8192, T=1024, H=8.
// v7 = v6 + trans-use hazard fix. v6 failed correctness (absmax 0.34): zero wait
// states between v_exp_f32 write and v_add_f32 read (and rcp->fma had only 1).
// CDNA trans ops need manually-inserted wait states before result consumption;
// compiler does this for builtins (v5 passed), my asm must do it explicitly.
// Step: r' = rcp(2^u + 1), u = pre + sum_m wq[m]*r[j^m]; h = 1-2r folded into
// weights/bias/FC. Matvec fused: 1 mov_dpp + 8 fmac(_dpp) instead of 7 mov + 8 fma.

#define T_LEN 1024
#define DPP_XOR1 0xB1   // quad_perm(1,0,3,2)
#define DPP_XOR2 0x4E   // quad_perm(2,3,0,1)
#define DPP_XOR7 0x141  // row_half_mirror
#define K_2LN2 2.8853900817779268f

template <int CTRL>
__device__ __forceinline__ float fdpp(float v) {
    int i = __builtin_bit_cast(int, v);
    int r = __builtin_amdgcn_mov_dpp(i, CTRL, 0xF, 0xF, true);
    return __builtin_bit_cast(float, r);
}

__device__ __forceinline__ float fast_sigmoid(float z) {
    float e = __builtin_amdgcn_exp2f(z * -1.4426950408889634f);
    return __builtin_amdgcn_rcpf(1.0f + e);
}

// Hazard spacing audit:
//  exp2 -> s_nop 1 (2 states) -> add reads e        : trans-use OK (needs 1-2)
//  rcp  -> s_nop 1 (2 states) -> fma reads r        : trans-use OK
//  rcp  -> s_nop + fma (3+ slots) -> mov_dpp DPP-reads r : DPP-after-write OK (needs 2)
//  mov_dpp writes m7 -> first DPP-read of m7 at distance 5 : OK
#define STEP(PRE)                                                              \
    asm volatile(                                                              \
        "v_fma_f32 %[u], %[r], %[w0], %[p]\n\t"                                \
        "v_mov_b32_dpp %[m7], %[r] row_half_mirror row_mask:0xf bank_mask:0xf\n\t" \
        "v_fmac_f32_dpp %[u], %[r], %[w1] quad_perm:[1,0,3,2] row_mask:0xf bank_mask:0xf\n\t" \
        "v_fmac_f32_dpp %[u], %[r], %[w2] quad_perm:[2,3,0,1] row_mask:0xf bank_mask:0xf\n\t" \
        "v_fmac_f32_dpp %[u], %[r], %[w3] quad_perm:[3,2,1,0] row_mask:0xf bank_mask:0xf\n\t" \
        "v_fmac_f32 %[u], %[m7], %[w7]\n\t"                                    \
        "v_fmac_f32_dpp %[u], %[m7], %[w4] quad_perm:[3,2,1,0] row_mask:0xf bank_mask:0xf\n\t" \
        "v_fmac_f32_dpp %[u], %[m7], %[w5] quad_perm:[2,3,0,1] row_mask:0xf bank_mask:0xf\n\t" \
        "v_fmac_f32_dpp %[u], %[m7], %[w6] quad_perm:[1,0,3,2] row_mask:0xf bank_mask:0xf\n\t" \
        "v_exp_f32 %[e], %[u]\n\t"                                             \
        "s_nop 1\n\t"                                                          \
        "v_add_f32 %[u], 1.0, %[e]\n\t"                                        \
        "v_rcp_f32 %[r], %[u]\n\t"                                             \
        "s_nop 1\n\t"                                                          \
        : [r]"+v"(r), [u]"=&v"(u_t), [e]"=&v"(e_t), [m7]"=&v"(m7_t)            \
        : [p]"v"(PRE), [w0]"v"(wq0), [w1]"v"(wq1), [w2]"v"(wq2),               \
          [w3]"v"(wq3), [w4]"v"(wq4), [w5]"v"(wq5), [w6]"v"(wq6),              \
          [w7]"v"(wq7))

__global__ __launch_bounds__(256) void rnn_oct_asm_kernel(
    const float* __restrict__ x, const float* __restrict__ W_ih,
    const float* __restrict__ W_hh, const float* __restrict__ b_ih,
    const float* __restrict__ b_hh, const float* __restrict__ W_fc,
    const float* __restrict__ b_fc, float* __restrict__ out, int B)
{
    const int tid = blockIdx.x * 256 + threadIdx.x;
    const int j = tid & 7;        // state element
    const int b = tid >> 3;       // batch
    if (b >= B) return;

    // wq[m] = -2K * W_hh[j][j^m];  rowsum folds into bias (h = 1-2r)
    float wv0 = W_hh[j * 8 + (j ^ 0)];
    float wv1 = W_hh[j * 8 + (j ^ 1)];
    float wv2 = W_hh[j * 8 + (j ^ 2)];
    float wv3 = W_hh[j * 8 + (j ^ 3)];
    float wv4 = W_hh[j * 8 + (j ^ 4)];
    float wv5 = W_hh[j * 8 + (j ^ 5)];
    float wv6 = W_hh[j * 8 + (j ^ 6)];
    float wv7 = W_hh[j * 8 + (j ^ 7)];
    float rowsum = ((wv0 + wv1) + (wv2 + wv3)) + ((wv4 + wv5) + (wv6 + wv7));
    const float wq0 = -2.0f * K_2LN2 * wv0;
    const float wq1 = -2.0f * K_2LN2 * wv1;
    const float wq2 = -2.0f * K_2LN2 * wv2;
    const float wq3 = -2.0f * K_2LN2 * wv3;
    const float wq4 = -2.0f * K_2LN2 * wv4;
    const float wq5 = -2.0f * K_2LN2 * wv5;
    const float wq6 = -2.0f * K_2LN2 * wv6;
    const float wq7 = -2.0f * K_2LN2 * wv7;
    const float biasp = K_2LN2 * (b_ih[j] + b_hh[j] + rowsum);
    const float wihp  = K_2LN2 * W_ih[j];

    const float wfc = W_fc[j];
    float sw = wfc;                       // group-sum of W_fc
    sw += fdpp<DPP_XOR1>(sw);
    sw += fdpp<DPP_XOR2>(sw);
    sw += fdpp<DPP_XOR7>(sw);
    const float cfc  = b_fc[0] + sw;      // bfc + sum_j wfc[j]
    const float wfc2 = -2.0f * wfc;

    const float* xb = x + (size_t)b * T_LEN;
    float r = 0.5f;                       // h=0 -> r=0.5
    float u_t, e_t, m7_t;

    // 16-step chunks: extract pre[16], then refill A regs (loads hide under steps).
    float4 A0 = *(const float4*)(xb + 0);
    float4 A1 = *(const float4*)(xb + 4);
    float4 A2 = *(const float4*)(xb + 8);
    float4 A3 = *(const float4*)(xb + 12);

#pragma unroll 1
    for (int t0 = 0; t0 < T_LEN; t0 += 16) {
        float pre[16];
        pre[0]  = __builtin_fmaf(A0.x, wihp, biasp);
        pre[1]  = __builtin_fmaf(A0.y, wihp, biasp);
        pre[2]  = __builtin_fmaf(A0.z, wihp, biasp);
        pre[3]  = __builtin_fmaf(A0.w, wihp, biasp);
        pre[4]  = __builtin_fmaf(A1.x, wihp, biasp);
        pre[5]  = __builtin_fmaf(A1.y, wihp, biasp);
        pre[6]  = __builtin_fmaf(A1.z, wihp, biasp);
        pre[7]  = __builtin_fmaf(A1.w, wihp, biasp);
        pre[8]  = __builtin_fmaf(A2.x, wihp, biasp);
        pre[9]  = __builtin_fmaf(A2.y, wihp, biasp);
        pre[10] = __builtin_fmaf(A2.z, wihp, biasp);
        pre[11] = __builtin_fmaf(A2.w, wihp, biasp);
        pre[12] = __builtin_fmaf(A3.x, wihp, biasp);
        pre[13] = __builtin_fmaf(A3.y, wihp, biasp);
        pre[14] = __builtin_fmaf(A3.z, wihp, biasp);
        pre[15] = __builtin_fmaf(A3.w, wihp, biasp);

        if (t0 + 16 < T_LEN) {            // refill consumed regs
            A0 = *(const float4*)(xb + t0 + 16);
            A1 = *(const float4*)(xb + t0 + 20);
            A2 = *(const float4*)(xb + t0 + 24);
            A3 = *(const float4*)(xb + t0 + 28);
        }

#pragma unroll
        for (int i = 0; i < 16; ++i)
            STEP(pre[i]);
    }

    // out[b] = sigmoid(cfc + sum_j wfc2[j]*r[j])
    float sv = r * wfc2;
    sv += fdpp<DPP_XOR1>(sv);
    sv += fdpp<DPP_XOR2>(sv);
    sv += fdpp<DPP_XOR7>(sv);
    if (j == 0) out[b] = fast_sigmoid(sv + cfc);
}

extern "C" void kernel_launch(void* const* d_in, const int* in_sizes, int n_in,
                              void* d_out, int out_size, void* d_ws, size_t ws_size,
                              hipStream_t stream) {
    const float* x    = (const float*)d_in[0];
    const float* W_ih = (const float*)d_in[1];
    const float* W_hh = (const float*)d_in[2];
    const float* b_ih = (const float*)d_in[3];
    const float* b_hh = (const float*)d_in[4];
    const float* W_fc = (const float*)d_in[5];
    const float* b_fc = (const float*)d_in[6];
    float* out = (float*)d_out;

    const int B = in_sizes[0] / T_LEN;     // 8192
    const int threads = B * 8;             // 65536 threads = 1024 waves = 1/SIMD
    const int grid = threads / 256;
    rnn_oct_asm_kernel<<<grid, 256, 0, stream>>>(x, W_ih, W_hh, b_ih, b_hh, W_fc, b_fc, out, B);
}